// Round 3
// baseline (395.488 us; speedup 1.0000x reference)
//
#include <hip/hip_runtime.h>
#include <hip/hip_fp16.h>
#include <math.h>

// B=16384, C=72, H=34, IN_CH=12, GROWTH=12, n=5
// out: (B, 84, 34) = concat([x, conv3x1(h)], ch)
// xxx channel map: region r=c/12, src = c + dd[r], dd={0,+36,+12,-12,-36,0}
// (involution). x channel cx feeds xxx channel cx+dd[cx/12] with gate index
// sidx[cx/12] = {0,4,3,2,1,5}. BN over xxx via gate-scaled per-batch row sums.
//
// Conv via MFMA (16x16x32 f16): O[o,hh] = sum_k W_k[o,:]·H[:,hh+k-1].
// Weight A-fragments (9) live in VGPRs (no per-channel weight refetch; the
// scalar conv was s_load-bound: SMEM+DS share lgkmcnt, SMEM out-of-order).

#define BN_EPS 1e-5f

// ws layout (float offsets)
#define WS_S    0      // 72
#define WS_SS   72     // 72
#define WS_A    144    // 72
#define WS_B    216    // 72
#define WS_WT   288    // 9 A-frags as fp16 [frag][lane][8]
#define WS_GATE 3744   // B*6 gates; partials follow at WS_GATE + B*6
#define K1_BLOCKS 512

typedef _Float16 f16x8 __attribute__((ext_vector_type(8)));
typedef float f32x4 __attribute__((ext_vector_type(4)));

__device__ __forceinline__ float sigmoidf_(float z) { return 1.f / (1.f + expf(-z)); }

// ---------------------------------------------------------------------------
// K1: gates + per-block BN partial sums. thread=(g,c) reads 34 floats direct
// from global (17 float2; wave footprint 8.7KB stays L1-resident -> coalesced
// over the unrolled loop). No LDS staging. Partials out, no atomics.
// ---------------------------------------------------------------------------
__global__ __launch_bounds__(256) void k1_stats(const float* __restrict__ x,
                                                const float* __restrict__ fw,
                                                const float* __restrict__ fb,
                                                float* __restrict__ ws,
                                                float* __restrict__ part,
                                                int B, int nTrip)
{
    __shared__ float rs_s[3][72], rss_s[3][72], wsum_s[3][72];
    __shared__ float lm_s[3][6];
    __shared__ float sc_s[3][8];
    __shared__ float Sacc[144];

    const int tid = threadIdx.x;
    const int g = tid / 72;          // batch-in-trip (0..2 for tid<216)
    const int c = tid - g * 72;      // channel
    if (tid < 144) Sacc[tid] = 0.f;

    for (int t = blockIdx.x; t < nTrip; t += K1_BLOCKS) {
        const int b0 = t * 3;

        if (tid < 216 && b0 + g < B) {
            const float2* p = (const float2*)(x + (size_t)(b0 + g) * 2448 + c * 34);
            float rs = 0.f, rss = 0.f, wsm = 0.f;
#pragma unroll
            for (int i = 0; i < 17; ++i) {
                float2 v = p[i];
                rs += v.x + v.y;
                rss = fmaf(v.x, v.x, fmaf(v.y, v.y, rss));
                wsm = fmaf(v.x, fw[2 * i], fmaf(v.y, fw[2 * i + 1], wsm));
            }
            rs_s[g][c] = rs; rss_s[g][c] = rss; wsum_s[g][c] = wsm;
        }
        __syncthreads();

        // region sums -> lm (18 threads)
        if (tid < 18) {
            int gg = tid / 6, r = tid - gg * 6;
            float s = 0.f;
#pragma unroll
            for (int k = 0; k < 12; ++k) s += wsum_s[gg][r * 12 + k];
            lm_s[gg][r] = s * (1.f / 12.f) + fb[0];
        }
        __syncthreads();

        // gates (3 threads)
        if (tid < 3 && b0 + tid < B) {
            float lin_out = lm_s[tid][5];
            float sc[6];
            sc[0] = sigmoidf_(lin_out + lm_s[tid][0]);  // g1
            sc[1] = sigmoidf_(lm_s[tid][4] + lin_out);  // gates[3]
            sc[2] = sigmoidf_(lm_s[tid][3] + lin_out);  // gates[2]
            sc[3] = sigmoidf_(lm_s[tid][2] + lin_out);  // gates[1]
            sc[4] = sigmoidf_(lm_s[tid][1] + lin_out);  // gates[0]
            sc[5] = 1.f;
            float* gb = ws + WS_GATE + (size_t)(b0 + tid) * 6;
#pragma unroll
            for (int r = 0; r < 6; ++r) { sc_s[tid][r] = sc[r]; gb[r] = sc[r]; }
        }
        __syncthreads();

        // BN stat accumulation (72 threads), src permutation
        if (tid < 72) {
            const int r = tid / 12;
            const int dd[6] = {0, 36, 12, -12, -36, 0};
            const int src = tid + dd[r];
            float a = 0.f, q = 0.f;
#pragma unroll
            for (int gg = 0; gg < 3; ++gg) {
                if (b0 + gg < B) {
                    float s = sc_s[gg][r];
                    a = fmaf(s, rs_s[gg][src], a);
                    q = fmaf(s * s, rss_s[gg][src], q);
                }
            }
            Sacc[tid] += a; Sacc[72 + tid] += q;
        }
        __syncthreads();
    }

    if (tid < 144) part[(size_t)tid * K1_BLOCKS + blockIdx.x] = Sacc[tid];
}

// ---------------------------------------------------------------------------
// K2a: reduce partials (144 blocks, one per stat channel; coalesced reads)
// ---------------------------------------------------------------------------
__global__ __launch_bounds__(256) void k2a_reduce(float* __restrict__ ws,
                                                  const float* __restrict__ part)
{
    const int ch = blockIdx.x;
    const float* p = part + (size_t)ch * K1_BLOCKS;
    float s = 0.f;
    for (int i = threadIdx.x; i < K1_BLOCKS; i += 256) s += p[i];
#pragma unroll
    for (int off = 32; off; off >>= 1) s += __shfl_down(s, off, 64);
    __shared__ float wsum[4];
    if ((threadIdx.x & 63) == 0) wsum[threadIdx.x >> 6] = s;
    __syncthreads();
    if (threadIdx.x == 0) ws[WS_S + ch] = wsum[0] + wsum[1] + wsum[2] + wsum[3];
}

// ---------------------------------------------------------------------------
// K2b: finalize BN affine + build the 9 MFMA A-fragments (fp16 weights).
// Frag f = shift*3 + ks. A[o = lane&15, k = (lane>>4)*8 + j], true channel
// ct = ks*32 + (lane>>4)*8 + j; zero outside (o<12, ct<72). For ks==2 the
// B-side gathers c = 64+j for ALL lane groups (dup); A is zero there anyway.
// ---------------------------------------------------------------------------
__global__ void k2b_finalize(const float* __restrict__ gamma,
                             const float* __restrict__ beta,
                             const float* __restrict__ cw,
                             float* __restrict__ ws, float invN)
{
    const int tid = threadIdx.x;
    if (tid < 72) {
        float S = ws[WS_S + tid], SS = ws[WS_SS + tid];
        float mu = S * invN;
        float var = SS * invN - mu * mu;
        float inv = rsqrtf(var + BN_EPS);
        float A = gamma[tid] * inv;
        ws[WS_A + tid] = A;
        ws[WS_B + tid] = beta[tid] - mu * A;
    }
    __half* wa = (__half*)(ws + WS_WT);
    for (int i = tid; i < 9 * 64 * 8; i += 256) {
        int j = i & 7;
        int lane = (i >> 3) & 63;
        int frag = i >> 9;                 // shift*3 + ks
        int shift = frag / 3, ks = frag - shift * 3;
        int o = lane & 15, grp = lane >> 4;
        int ct = ks * 32 + grp * 8 + j;    // true k (channel) index
        float v = (o < 12 && ct < 72) ? cw[o * 216 + ct * 3 + shift] : 0.f;
        wa[i] = __float2half(v);
    }
}

// ---------------------------------------------------------------------------
// per-element transform: gate+BN-affine+relu -> fp16 packed LDS write.
// A float4 of x never straddles a region boundary (408 % 4 == 0) and the
// permutation shifts whole regions, so 4 values pack into one 8B LDS write.
// ---------------------------------------------------------------------------
__device__ __forceinline__ void pack_h(int g, int v4, float4 q,
                                       const float2* __restrict__ ABs,
                                       const float* __restrict__ glf,
                                       __half* __restrict__ hs)
{
    const int ddc[6]  = {0, 36, 12, -12, -36, 0};
    const int sidx[6] = {0, 4, 3, 2, 1, 5};
    int rx = v4 / 102;              // region (uniform over the float4)
    int e  = v4 * 4;
    int cx0 = e / 34;
    int h0i = e - cx0 * 34;         // h of element 0 (0..33)
    int dd  = ddc[rx];
    int cd0 = cx0 + dd;
    float2 ab0 = ABs[cd0];
    float2 ab1 = ABs[cd0 + 1];
    float s = glf[g * 8 + sidx[rx]];
    float vv[4] = {q.x, q.y, q.z, q.w};
    __half hv[4];
#pragma unroll
    for (int j = 0; j < 4; ++j) {
        float2 ab = (h0i + j >= 34) ? ab1 : ab0;
        hv[j] = __float2half(fmaxf(fmaf(ab.x * s, vv[j], ab.y), 0.f));
    }
    union { __half2 h2; unsigned int u; } pa, pb;
    pa.h2 = __halves2half2(hv[0], hv[1]);
    pb.h2 = __halves2half2(hv[2], hv[3]);
    int dst = g * 2456 + 4 + e + dd * 34;      // multiple of 4 halfs
    *reinterpret_cast<uint2*>(&hs[dst]) = make_uint2(pa.u, pb.u);
}

// ---------------------------------------------------------------------------
// K3: transform + MFMA conv + output. 6 batches/block; h in LDS as fp16,
// per-batch stride 2456 halfs: [0..3]=zero pad, [4..2451]=h (channel rows
// contiguous, stride 34), [2452..2455]=zero pad. LDS ~30.2 KB -> 5 blocks/CU
// (pinned via launch_bounds; conv live set ~85 VGPR < 102 cap).
//
// Transform phase: 2-deep batched streaming (both float4 loads issued before
// any dependent store/pack) — the serial load->pack->store chain at MLP=1 was
// latency-bound (k3 at 2.4x its memory roofline, nothing saturated).
//
// Conv: 13 tiles/block (6 batches x cols{0-15,16-31} + shared tail tile for
// cols 32-33). Per tile: 9 B-frag gathers (8x ds_read_u16, lane groups at +8
// dword banks -> conflict-free) + 9 MFMA + 3 correction MFMAs cancelling the
// channel-edge wraparound on cols 0 / 33.
// ---------------------------------------------------------------------------
__global__ __launch_bounds__(256, 5) void k3_out(const float* __restrict__ x,
                                                 const float* __restrict__ ws,
                                                 float* __restrict__ out, int B)
{
    __shared__ __align__(16) __half hs[6 * 2456];  // 29472 B
    __shared__ float2 AB[73];                      // [72] = padding entry
    __shared__ float gl[6][8];

    const int tid = threadIdx.x;
    const int lane = tid & 63;
    const int wid = tid >> 6;
    const int b0 = blockIdx.x * 6;
    int nb = B - b0; if (nb > 6) nb = 6;

    // A-fragments: load once per wave, early (latency hides under transform).
    const __half* wa = (const __half*)(ws + WS_WT);
    f16x8 wA[9];
#pragma unroll
    for (int f = 0; f < 9; ++f)
        wA[f] = *(const f16x8*)(wa + (f * 64 + lane) * 8);

    if (tid < 73)
        AB[tid] = (tid < 72) ? make_float2(ws[WS_A + tid], ws[WS_B + tid])
                             : make_float2(0.f, 0.f);
    for (int t2 = tid; t2 < nb * 6; t2 += 256) {
        int g = t2 / 6, j = t2 - g * 6;
        gl[g][j] = ws[WS_GATE + (size_t)(b0 + g) * 6 + j];
    }
    // zero the 4-half pads (dwords {0,1,1226,1227} per batch region)
    if (tid < 24) {
        int g = tid >> 2, k = tid & 3;
        ((unsigned int*)hs)[g * 1228 + ((k < 2) ? k : (1224 + k))] = 0u;
    }
    // last block only: zero unwritten batch regions so MFMA garbage stays finite
    if (nb < 6) {
        for (int i = tid; i < (6 - nb) * 1228; i += 256)
            ((unsigned int*)hs)[nb * 1228 + i] = 0u;
    }
    __syncthreads();

    // transform: 2-deep batched (MLP=2 per wave)
    {
        const int total = nb * 612;
        const float* glf = &gl[0][0];
        for (int idx = tid; idx < total; idx += 512) {
            const int idxB = idx + 256;
            const bool okB = idxB < total;

            int gA = idx / 612, vA = idx - gA * 612;
            size_t bA = (size_t)(b0 + gA);
            float4 qA = ((const float4*)(x + bA * 2448))[vA];

            int gB = 0, vB = 0; size_t bB = 0;
            float4 qB = qA;
            if (okB) {
                gB = idxB / 612; vB = idxB - gB * 612;
                bB = (size_t)(b0 + gB);
                qB = ((const float4*)(x + bB * 2448))[vB];
            }

            ((float4*)(out + bA * 2856))[vA] = qA;
            if (okB) ((float4*)(out + bB * 2856))[vB] = qB;

            pack_h(gA, vA, qA, AB, glf, hs);
            if (okB) pack_h(gB, vB, qB, AB, glf, hs);
        }
    }
    __syncthreads();

    // conv via MFMA. Tile t<12: g=t>>1, cols (t&1)*16..+15. t==12: tail tile,
    // lanes sub=0..11 cover (g=sub>>1, col=32+(sub&1)).
    const int sub = lane & 15, grp = lane >> 4;
    for (int t = wid; t < 13; t += 4) {
        const bool tail = (t == 12);
        int g, col;
        if (!tail) { g = t >> 1; col = (t & 1) * 16 + sub; }
        else       { g = (sub < 12) ? (sub >> 1) : 0; col = 32 + (sub & 1); }
        if (!tail && g >= nb) continue;

        const __half* hb = &hs[g * 2456 + 4];
        f32x4 acc = {0.f, 0.f, 0.f, 0.f};
        f16x8 save0, save1, save2;
        const bool needc = tail || ((t & 1) == 0);   // which tiles need corr
        const int  csh   = tail ? 2 : 0;             // corr shift (col33 / col0)

#pragma unroll
        for (int ks = 0; ks < 3; ++ks) {
            const int cb = (ks < 2) ? (ks * 32 + grp * 8) : 64;
            const __half* hc = hb + cb * 34 + col;
#pragma unroll
            for (int sh = 0; sh < 3; ++sh) {
                f16x8 bf;
#pragma unroll
                for (int j = 0; j < 8; ++j)
                    ((unsigned short*)&bf)[j] =
                        *(const unsigned short*)(hc + j * 34 + (sh - 1));
                if (needc && sh == csh) {
                    if (ks == 0) save0 = bf;
                    else if (ks == 1) save1 = bf;
                    else save2 = bf;
                }
                acc = __builtin_amdgcn_mfma_f32_16x16x32_f16(
                          wA[sh * 3 + ks], bf, acc, 0, 0, 0);
            }
        }

        // corrections: subtract the wrapped-around contribution on col 0
        // (shift 0: h[c,-1] read h[c-1,33]) or col 33 (shift 2: h[c,34] read
        // h[c+1,0]). B~ = lane-masked, sign-flipped copy of the saved frag;
        // at the true boundaries (c=0 / c=71) the saved value is the zero
        // pad, so the correction self-cancels. All-lane uniform MFMA.
        if (needc) {
            const bool m = tail ? (((sub & 1) == 1) && sub < 12) : (sub == 0);
#pragma unroll
            for (int ks = 0; ks < 3; ++ks) {
                const f16x8& sv = (ks == 0) ? save0 : (ks == 1) ? save1 : save2;
                f16x8 bt;
#pragma unroll
                for (int w = 0; w < 4; ++w)
                    ((unsigned int*)&bt)[w] =
                        m ? (((const unsigned int*)&sv)[w] ^ 0x80008000u) : 0u;
                acc = __builtin_amdgcn_mfma_f32_16x16x32_f16(
                          wA[csh * 3 + ks], bt, acc, 0, 0, 0);
            }
        }

        // store: D[col=sub, row=grp*4+j]. Rows 12..15 are weight pad -> skip.
        const bool gok = tail ? (sub < 12 && g < nb) : true;
        if (gok) {
            float* op = out + (size_t)(b0 + g) * 2856 + 2448 + col;
#pragma unroll
            for (int j = 0; j < 4; ++j) {
                int o = grp * 4 + j;
                if (o < 12) op[o * 34] = acc[j];
            }
        }
    }
}

extern "C" void kernel_launch(void* const* d_in, const int* in_sizes, int n_in,
                              void* d_out, int out_size, void* d_ws, size_t ws_size,
                              hipStream_t stream)
{
    const float* x     = (const float*)d_in[0];
    const float* gamma = (const float*)d_in[1];
    const float* beta  = (const float*)d_in[2];
    const float* cw    = (const float*)d_in[3];
    const float* fw    = (const float*)d_in[4];
    const float* fb    = (const float*)d_in[5];
    float* out = (float*)d_out;
    float* ws  = (float*)d_ws;

    const int B = in_sizes[0] / (72 * 34);
    const int nTrip = (B + 2) / 3;
    float* part = ws + WS_GATE + (size_t)B * 6;   // 144*K1_BLOCKS floats

    k1_stats<<<K1_BLOCKS, 256, 0, stream>>>(x, fw, fb, ws, part, B, nTrip);
    k2a_reduce<<<144, 256, 0, stream>>>(ws, part);
    k2b_finalize<<<1, 256, 0, stream>>>(gamma, beta, cw, ws, 1.f / ((float)B * 34.f));
    k3_out<<<(B + 5) / 6, 256, 0, stream>>>(x, ws, out, B);
}

// Round 5
// 385.480 us; speedup vs baseline: 1.0260x; 1.0260x over previous
//
#include <hip/hip_runtime.h>
#include <hip/hip_fp16.h>
#include <math.h>

// B=16384, C=72, H=34, IN_CH=12, GROWTH=12, n=5
// out: (B, 84, 34) = concat([x, conv3x1(h)], ch)
// xxx channel map: region r=c/12, src = c + dd[r], dd={0,+36,+12,-12,-36,0}
// (involution). x channel cx feeds xxx channel cx+dd[cx/12] with gate index
// sidx[cx/12] = {0,4,3,2,1,5}. BN over xxx via gate-scaled per-batch row sums.
//
// Conv via MFMA (16x16x32 f16): O[o,hh] = sum_k W_k[o,:]·H[:,hh+k-1].
// Weight A-fragments (9) live in VGPRs (no per-channel weight refetch; the
// scalar conv was s_load-bound: SMEM+DS share lgkmcnt, SMEM out-of-order).
//
// K1 is LDS-staged: the old direct-global row reads (17 float2 @ 136B lane
// stride) made every VMEM instruction touch ~64 cache lines (TA-bound).
// Now: coalesced float4 global->LDS, row sums from LDS (2-way bank alias =
// free), up to 4 blocks/CU instead of 2.

#define BN_EPS 1e-5f

// ws layout (float offsets)
#define WS_S    0      // 72
#define WS_SS   72     // 72
#define WS_WT   288    // 9 A-frags as fp16 [frag][lane][8] (4608 halfs)
#define WS_GATE 3744   // B*6 gates; partials follow at WS_GATE + B*6

typedef _Float16 f16x8 __attribute__((ext_vector_type(8)));
typedef float f32x4 __attribute__((ext_vector_type(4)));

__device__ __forceinline__ float sigmoidf_(float z) { return 1.f / (1.f + expf(-z)); }

// ---------------------------------------------------------------------------
// K1: gates + per-block BN partial sums. Per trip (3 batches): coalesced
// float4 stage of 3*2448 floats into LDS, then thread=(g,c) row sums from
// LDS. Partials out, no atomics.
// ---------------------------------------------------------------------------
__global__ __launch_bounds__(256) void k1_stats(const float* __restrict__ x,
                                                const float* __restrict__ fw,
                                                const float* __restrict__ fb,
                                                float* __restrict__ ws,
                                                float* __restrict__ part,
                                                int B, int nTrip)
{
    __shared__ float xs[3 * 2448];                   // 29376 B
    __shared__ float rs_s[3][72], rss_s[3][72], wsum_s[3][72];
    __shared__ float lm_s[3][6];
    __shared__ float sc_s[3][8];
    __shared__ float Sacc[144];

    const int tid = threadIdx.x;
    const int g = tid / 72;          // batch-in-trip (0..2 for tid<216)
    const int c = tid - g * 72;      // channel
    if (tid < 144) Sacc[tid] = 0.f;

    for (int t = blockIdx.x; t < nTrip; t += gridDim.x) {
        const int b0 = t * 3;
        int nbt = B - b0; if (nbt > 3) nbt = 3;

        // coalesced stage: nbt*612 float4s
        {
            const float4* xp = (const float4*)(x + (size_t)b0 * 2448);
            const int nf4 = nbt * 612;
            for (int i = tid; i < nf4; i += 256)
                ((float4*)xs)[i] = xp[i];
        }
        __syncthreads();

        if (tid < 216 && g < nbt) {
            const float2* p = (const float2*)(xs + (g * 72 + c) * 34);
            float rs = 0.f, rss = 0.f, wsm = 0.f;
#pragma unroll
            for (int i = 0; i < 17; ++i) {
                float2 v = p[i];
                rs += v.x + v.y;
                rss = fmaf(v.x, v.x, fmaf(v.y, v.y, rss));
                wsm = fmaf(v.x, fw[2 * i], fmaf(v.y, fw[2 * i + 1], wsm));
            }
            rs_s[g][c] = rs; rss_s[g][c] = rss; wsum_s[g][c] = wsm;
        }
        __syncthreads();

        // region sums -> lm (18 threads)
        if (tid < 18) {
            int gg = tid / 6, r = tid - gg * 6;
            float s = 0.f;
#pragma unroll
            for (int k = 0; k < 12; ++k) s += wsum_s[gg][r * 12 + k];
            lm_s[gg][r] = s * (1.f / 12.f) + fb[0];
        }
        __syncthreads();

        // gates (3 threads)
        if (tid < 3 && b0 + tid < B) {
            float lin_out = lm_s[tid][5];
            float sc[6];
            sc[0] = sigmoidf_(lin_out + lm_s[tid][0]);  // g1
            sc[1] = sigmoidf_(lm_s[tid][4] + lin_out);  // gates[3]
            sc[2] = sigmoidf_(lm_s[tid][3] + lin_out);  // gates[2]
            sc[3] = sigmoidf_(lm_s[tid][2] + lin_out);  // gates[1]
            sc[4] = sigmoidf_(lm_s[tid][1] + lin_out);  // gates[0]
            sc[5] = 1.f;
            float* gb = ws + WS_GATE + (size_t)(b0 + tid) * 6;
#pragma unroll
            for (int r = 0; r < 6; ++r) { sc_s[tid][r] = sc[r]; gb[r] = sc[r]; }
        }
        __syncthreads();

        // BN stat accumulation (72 threads), src permutation
        if (tid < 72) {
            const int r = tid / 12;
            const int dd[6] = {0, 36, 12, -12, -36, 0};
            const int src = tid + dd[r];
            float a = 0.f, q = 0.f;
#pragma unroll
            for (int gg = 0; gg < 3; ++gg) {
                if (gg < nbt) {
                    float s = sc_s[gg][r];
                    a = fmaf(s, rs_s[gg][src], a);
                    q = fmaf(s * s, rss_s[gg][src], q);
                }
            }
            Sacc[tid] += a; Sacc[72 + tid] += q;
        }
        __syncthreads();
    }

    if (tid < 144) part[(size_t)tid * gridDim.x + blockIdx.x] = Sacc[tid];
}

// ---------------------------------------------------------------------------
// K2a: blocks 0..143 reduce partials (one per stat channel, coalesced);
// blocks 144..152 build the 9 MFMA A-fragments (fp16 weights) in parallel.
// Frag f = shift*3 + ks. A[o = lane&15, k = (lane>>4)*8 + j], true channel
// ct = ks*32 + (lane>>4)*8 + j; zero outside (o<12, ct<72). For ks==2 the
// B-side gathers c = 64+j for ALL lane groups (dup); A is zero there anyway.
// ---------------------------------------------------------------------------
__global__ __launch_bounds__(256) void k2a_reduce(float* __restrict__ ws,
                                                  const float* __restrict__ part,
                                                  const float* __restrict__ cw,
                                                  int nblk)
{
    const int bid = blockIdx.x;
    if (bid < 144) {
        const float* p = part + (size_t)bid * nblk;
        float s = 0.f;
        for (int i = threadIdx.x; i < nblk; i += 256) s += p[i];
#pragma unroll
        for (int off = 32; off; off >>= 1) s += __shfl_down(s, off, 64);
        __shared__ float wsum[4];
        if ((threadIdx.x & 63) == 0) wsum[threadIdx.x >> 6] = s;
        __syncthreads();
        if (threadIdx.x == 0) ws[WS_S + bid] = wsum[0] + wsum[1] + wsum[2] + wsum[3];
    } else {
        __half* wa = (__half*)(ws + WS_WT);
        const int base = (bid - 144) * 512;
        for (int i = base + threadIdx.x; i < base + 512; i += 256) {
            int j = i & 7;
            int lane = (i >> 3) & 63;
            int frag = i >> 9;                 // shift*3 + ks
            int shift = frag / 3, ks = frag - shift * 3;
            int o = lane & 15, grp = lane >> 4;
            int ct = ks * 32 + grp * 8 + j;    // true k (channel) index
            float v = (o < 12 && ct < 72) ? cw[o * 216 + ct * 3 + shift] : 0.f;
            wa[i] = __float2half(v);
        }
    }
}

// ---------------------------------------------------------------------------
// per-element transform: gate+BN-affine+relu -> fp16 packed LDS write.
// A float4 of x never straddles a region boundary (408 % 4 == 0) and the
// permutation shifts whole regions, so 4 values pack into one 8B LDS write.
// ---------------------------------------------------------------------------
__device__ __forceinline__ void pack_h(int g, int v4, float4 q,
                                       const float2* __restrict__ ABs,
                                       const float* __restrict__ glf,
                                       __half* __restrict__ hs)
{
    const int ddc[6]  = {0, 36, 12, -12, -36, 0};
    const int sidx[6] = {0, 4, 3, 2, 1, 5};
    int rx = v4 / 102;              // region (uniform over the float4)
    int e  = v4 * 4;
    int cx0 = e / 34;
    int h0i = e - cx0 * 34;         // h of element 0 (0..33)
    int dd  = ddc[rx];
    int cd0 = cx0 + dd;
    float2 ab0 = ABs[cd0];
    float2 ab1 = ABs[cd0 + 1];
    float s = glf[g * 8 + sidx[rx]];
    float vv[4] = {q.x, q.y, q.z, q.w};
    __half hv[4];
#pragma unroll
    for (int j = 0; j < 4; ++j) {
        float2 ab = (h0i + j >= 34) ? ab1 : ab0;
        hv[j] = __float2half(fmaxf(fmaf(ab.x * s, vv[j], ab.y), 0.f));
    }
    union { __half2 h2; unsigned int u; } pa, pb;
    pa.h2 = __halves2half2(hv[0], hv[1]);
    pb.h2 = __halves2half2(hv[2], hv[3]);
    int dst = g * 2456 + 4 + e + dd * 34;      // multiple of 4 halfs
    *reinterpret_cast<uint2*>(&hs[dst]) = make_uint2(pa.u, pb.u);
}

// ---------------------------------------------------------------------------
// K3: transform + MFMA conv + output. 6 batches/block; h in LDS as fp16,
// per-batch stride 2456 halfs: [0..3]=zero pad, [4..2451]=h (channel rows
// contiguous, stride 34), [2452..2455]=zero pad. BN affine computed in-block
// from WS_S/WS_SS (k2b folded away). LDS ~30.2 KB -> 5 blocks/CU.
//
// Conv: 13 tiles/block (6 batches x cols{0-15,16-31} + shared tail tile for
// cols 32-33). Per tile: 9 B-frag gathers (8x ds_read_u16, lane groups at +8
// dword banks -> conflict-free) + 9 MFMA + 3 correction MFMAs cancelling the
// channel-edge wraparound on cols 0 / 33.
// ---------------------------------------------------------------------------
__global__ __launch_bounds__(256) void k3_out(const float* __restrict__ x,
                                              const float* __restrict__ ws,
                                              const float* __restrict__ gamma,
                                              const float* __restrict__ beta,
                                              float* __restrict__ out, int B,
                                              float invN)
{
    __shared__ __align__(16) __half hs[6 * 2456];  // 29472 B
    __shared__ float2 AB[73];                      // [72] = padding entry
    __shared__ float gl[6][8];

    const int tid = threadIdx.x;
    const int lane = tid & 63;
    const int wid = tid >> 6;
    const int b0 = blockIdx.x * 6;
    int nb = B - b0; if (nb > 6) nb = 6;

    // A-fragments: load once per wave, early (latency hides under transform).
    const __half* wa = (const __half*)(ws + WS_WT);
    f16x8 wA[9];
#pragma unroll
    for (int f = 0; f < 9; ++f)
        wA[f] = *(const f16x8*)(wa + (f * 64 + lane) * 8);

    if (tid < 73) {
        if (tid < 72) {
            float S = ws[WS_S + tid], SS = ws[WS_SS + tid];
            float mu = S * invN;
            float var = SS * invN - mu * mu;
            float inv = rsqrtf(var + BN_EPS);
            float A = gamma[tid] * inv;
            AB[tid] = make_float2(A, beta[tid] - mu * A);
        } else {
            AB[72] = make_float2(0.f, 0.f);
        }
    }
    for (int t2 = tid; t2 < nb * 6; t2 += 256) {
        int g = t2 / 6, j = t2 - g * 6;
        gl[g][j] = ws[WS_GATE + (size_t)(b0 + g) * 6 + j];
    }
    // zero the 4-half pads (dwords {0,1,1226,1227} per batch region)
    if (tid < 24) {
        int g = tid >> 2, k = tid & 3;
        ((unsigned int*)hs)[g * 1228 + ((k < 2) ? k : (1224 + k))] = 0u;
    }
    // last block only: zero unwritten batch regions so MFMA garbage stays finite
    if (nb < 6) {
        for (int i = tid; i < (6 - nb) * 1228; i += 256)
            ((unsigned int*)hs)[nb * 1228 + i] = 0u;
    }
    __syncthreads();

    // transform: x float4 -> passthrough out + packed fp16 h into LDS
    {
        const float* glf = &gl[0][0];
        for (int idx = tid; idx < nb * 612; idx += 256) {
            int g = idx / 612, v4 = idx - g * 612;
            size_t b = (size_t)(b0 + g);
            float4 q = ((const float4*)(x + b * 2448))[v4];
            ((float4*)(out + b * 2856))[v4] = q;
            pack_h(g, v4, q, AB, glf, hs);
        }
    }
    __syncthreads();

    // conv via MFMA. Tile t<12: g=t>>1, cols (t&1)*16..+15. t==12: tail tile,
    // lanes sub=0..11 cover (g=sub>>1, col=32+(sub&1)).
    const int sub = lane & 15, grp = lane >> 4;
    for (int t = wid; t < 13; t += 4) {
        const bool tail = (t == 12);
        int g, col;
        if (!tail) { g = t >> 1; col = (t & 1) * 16 + sub; }
        else       { g = (sub < 12) ? (sub >> 1) : 0; col = 32 + (sub & 1); }
        if (!tail && g >= nb) continue;

        const __half* hb = &hs[g * 2456 + 4];
        f32x4 acc = {0.f, 0.f, 0.f, 0.f};
        f16x8 save0, save1, save2;
        const bool needc = tail || ((t & 1) == 0);   // which tiles need corr
        const int  csh   = tail ? 2 : 0;             // corr shift (col33 / col0)

#pragma unroll
        for (int ks = 0; ks < 3; ++ks) {
            const int cb = (ks < 2) ? (ks * 32 + grp * 8) : 64;
            const __half* hc = hb + cb * 34 + col;
#pragma unroll
            for (int sh = 0; sh < 3; ++sh) {
                f16x8 bf;
#pragma unroll
                for (int j = 0; j < 8; ++j)
                    ((unsigned short*)&bf)[j] =
                        *(const unsigned short*)(hc + j * 34 + (sh - 1));
                if (needc && sh == csh) {
                    if (ks == 0) save0 = bf;
                    else if (ks == 1) save1 = bf;
                    else save2 = bf;
                }
                acc = __builtin_amdgcn_mfma_f32_16x16x32_f16(
                          wA[sh * 3 + ks], bf, acc, 0, 0, 0);
            }
        }

        // corrections: subtract the wrapped-around contribution on col 0
        // (shift 0: h[c,-1] read h[c-1,33]) or col 33 (shift 2: h[c,34] read
        // h[c+1,0]). B~ = lane-masked, sign-flipped copy of the saved frag;
        // at the true boundaries (c=0 / c=71) the saved value is the zero
        // pad, so the correction self-cancels. All-lane uniform MFMA.
        if (needc) {
            const bool m = tail ? (((sub & 1) == 1) && sub < 12) : (sub == 0);
#pragma unroll
            for (int ks = 0; ks < 3; ++ks) {
                const f16x8& sv = (ks == 0) ? save0 : (ks == 1) ? save1 : save2;
                f16x8 bt;
#pragma unroll
                for (int w = 0; w < 4; ++w)
                    ((unsigned int*)&bt)[w] =
                        m ? (((const unsigned int*)&sv)[w] ^ 0x80008000u) : 0u;
                acc = __builtin_amdgcn_mfma_f32_16x16x32_f16(
                          wA[csh * 3 + ks], bt, acc, 0, 0, 0);
            }
        }

        // store: D[col=sub, row=grp*4+j]. Rows 12..15 are weight pad -> skip.
        const bool gok = tail ? (sub < 12 && g < nb) : true;
        if (gok) {
            float* op = out + (size_t)(b0 + g) * 2856 + 2448 + col;
#pragma unroll
            for (int j = 0; j < 4; ++j) {
                int o = grp * 4 + j;
                if (o < 12) op[o * 34] = acc[j];
            }
        }
    }
}

extern "C" void kernel_launch(void* const* d_in, const int* in_sizes, int n_in,
                              void* d_out, int out_size, void* d_ws, size_t ws_size,
                              hipStream_t stream)
{
    const float* x     = (const float*)d_in[0];
    const float* gamma = (const float*)d_in[1];
    const float* beta  = (const float*)d_in[2];
    const float* cw    = (const float*)d_in[3];
    const float* fw    = (const float*)d_in[4];
    const float* fb    = (const float*)d_in[5];
    float* out = (float*)d_out;
    float* ws  = (float*)d_ws;

    const int B = in_sizes[0] / (72 * 34);
    const int nTrip = (B + 2) / 3;

    // adaptive k1 grid: partials need 144*nblk floats after WS_GATE + B*6.
    // Capacity ceiling ALWAYS wins (a forced floor above maxblk would write
    // past d_ws -> device corruption). Prior sessions ran 512 in this ws.
    int nblk = 1024;
    {
        long avail = (long)(ws_size / 4) - (WS_GATE + (long)B * 6);
        long maxblk = avail / 144;
        if (maxblk < 1) maxblk = 1;
        if ((long)nblk > maxblk) nblk = (int)maxblk;
    }
    float* part = ws + WS_GATE + (size_t)B * 6;

    k1_stats<<<nblk, 256, 0, stream>>>(x, fw, fb, ws, part, B, nTrip);
    k2a_reduce<<<153, 256, 0, stream>>>(ws, part, cw, nblk);
    k3_out<<<(B + 5) / 6, 256, 0, stream>>>(x, ws, gamma, beta, out, B,
                                            1.f / ((float)B * 34.f));
}